// Round 3
// baseline (231.100 us; speedup 1.0000x reference)
//
#include <hip/hip_runtime.h>

// Problem constants (from reference): B=64, S=8192, C=512
#define NROWS (64 * 8192)
#define C 512
#define WEIGHT 2.0f
#define NBLOCKS 2048
#define BLOCK 256                       // 4 waves per block
#define NWAVES (NBLOCKS * 4)            // 8192 waves
#define ITERS (NROWS / (2 * NWAVES))    // 32 iterations, 2 rows per iter (exact)

typedef float v4f __attribute__((ext_vector_type(4)));

// Per-row reduce: lane-local argmax over its 8 cols (strict > in ascending
// column order => first occurrence), 6-step shfl_xor butterfly (tie-break:
// smaller index), then a register-based gather of pre[row][t]: the owning
// lane already holds the value; select via cndmask chain + one __shfl.
__device__ __forceinline__ void row_reduce(v4f a, v4f b, int lane, int t, float& acc) {
    int baseA = lane * 4;
    float mval = a.x; int midx = baseA;
    if (a.y > mval) { mval = a.y; midx = baseA + 1; }
    if (a.z > mval) { mval = a.z; midx = baseA + 2; }
    if (a.w > mval) { mval = a.w; midx = baseA + 3; }
    int baseB = 256 + lane * 4;
    if (b.x > mval) { mval = b.x; midx = baseB; }
    if (b.y > mval) { mval = b.y; midx = baseB + 1; }
    if (b.z > mval) { mval = b.z; midx = baseB + 2; }
    if (b.w > mval) { mval = b.w; midx = baseB + 3; }

    #pragma unroll
    for (int off = 1; off < 64; off <<= 1) {
        float oval = __shfl_xor(mval, off);
        int   oidx = __shfl_xor(midx, off);
        if (oval > mval || (oval == mval && oidx < midx)) {
            mval = oval; midx = oidx;
        }
    }

    // Register gather of pre[row][t] (t is wave-uniform):
    // col t lives in lane (t&255)>>2, half a/b by t>=256, element t&3.
    bool hi = t >= 256;
    int  e = t & 3;
    int  owner = (t & 255) >> 2;
    float cx = hi ? b.x : a.x;
    float cy = hi ? b.y : a.y;
    float cz = hi ? b.z : a.z;
    float cw = hi ? b.w : a.w;
    float d0 = (e & 1) ? cy : cx;
    float d1 = (e & 1) ? cw : cz;
    float cand = (e & 2) ? d1 : d0;
    float g = __shfl(cand, owner);

    int d = midx - t;
    float w = (d == 1 || d == -1) ? WEIGHT : 1.0f;
    acc += w * g;
}

__global__ __launch_bounds__(BLOCK) void nll_rows_kernel(
    const float* __restrict__ pre,
    const int* __restrict__ y_true,
    float* __restrict__ partial) {
    const int lane = threadIdx.x & 63;
    const int wave = threadIdx.x >> 6;        // 0..3
    const int gwave = blockIdx.x * 4 + wave;  // global wave id

    const v4f* p = reinterpret_cast<const v4f*>(pre) + (size_t)gwave * (C / 4);
    const size_t rstride = (size_t)NWAVES * (C / 4);  // v4f elements per row-step

    float acc = 0.0f;
    int row = gwave;
    for (int it = 0; it < ITERS; ++it) {
        const v4f* p0 = p;
        const v4f* p1 = p + rstride;
        // Issue all 4 row loads + both y_true loads before any reduce work:
        // 2 rows of VMEM in flight per wave. Plain cached loads (nontemporal
        // measurably cost ~8% raw read BW on gfx950 — R2 post-mortem).
        v4f a0 = p0[lane];
        v4f b0 = p0[64 + lane];
        v4f a1 = p1[lane];
        v4f b1 = p1[64 + lane];
        int t0 = y_true[row];
        int t1 = y_true[row + NWAVES];

        row_reduce(a0, b0, lane, t0, acc);
        row_reduce(a1, b1, lane, t1, acc);

        p += 2 * rstride;
        row += 2 * NWAVES;
    }

    __shared__ float ssum[4];
    if (lane == 0) ssum[wave] = acc;  // acc is wave-uniform; lane 0's copy
    __syncthreads();
    if (threadIdx.x == 0) {
        partial[blockIdx.x] = ssum[0] + ssum[1] + ssum[2] + ssum[3];
    }
}

// Deterministic fixed-order reduction of the block partials.
__global__ __launch_bounds__(256) void nll_reduce_kernel(
    const float* __restrict__ partial, float* __restrict__ out, int n) {
    __shared__ float s[256];
    float acc = 0.0f;
    for (int i = threadIdx.x; i < n; i += 256) acc += partial[i];
    s[threadIdx.x] = acc;
    __syncthreads();
    for (int w = 128; w > 0; w >>= 1) {
        if (threadIdx.x < w) s[threadIdx.x] += s[threadIdx.x + w];
        __syncthreads();
    }
    if (threadIdx.x == 0) out[0] = s[0] * (1.0f / 64.0f);  // divide by B
}

extern "C" void kernel_launch(void* const* d_in, const int* in_sizes, int n_in,
                              void* d_out, int out_size, void* d_ws, size_t ws_size,
                              hipStream_t stream) {
    const float* pre = (const float*)d_in[0];
    const int* y_true = (const int*)d_in[1];
    float* out = (float*)d_out;
    float* partial = (float*)d_ws;  // NBLOCKS floats

    nll_rows_kernel<<<NBLOCKS, BLOCK, 0, stream>>>(pre, y_true, partial);
    nll_reduce_kernel<<<1, 256, 0, stream>>>(partial, out, NBLOCKS);
}

// Round 4
// 197.545 us; speedup vs baseline: 1.1699x; 1.1699x over previous
//
#include <hip/hip_runtime.h>

// Problem constants (from reference): B=64, S=8192, C=512
#define NROWS (64 * 8192)
#define C 512
#define WEIGHT 2.0f
#define NBLOCKS 2048
#define BLOCK 256                    // 4 waves per block
#define NWAVES (NBLOCKS * 4)         // 8192 waves
#define ITERS (NROWS / NWAVES)       // 64 rows per wave (exact)

typedef float v4f __attribute__((ext_vector_type(4)));

// Wave64 max via DPP (canonical GCN lane-63 reduction; max is idempotent so
// full row/bank masks are safe). Zero DS ops. Result valid in lane 63.
__device__ __forceinline__ float dpp_wave_max(float v) {
    const int NEGINF = 0xFF800000;  // -inf bits (old value for masked lanes)
#define DPP_STEP(ctrl)                                                        \
    v = fmaxf(v, __int_as_float(__builtin_amdgcn_update_dpp(                  \
                     NEGINF, __float_as_int(v), (ctrl), 0xf, 0xf, false)));
    DPP_STEP(0x111)  // row_shr:1
    DPP_STEP(0x112)  // row_shr:2
    DPP_STEP(0x114)  // row_shr:4
    DPP_STEP(0x118)  // row_shr:8
    DPP_STEP(0x142)  // row_bcast:15
    DPP_STEP(0x143)  // row_bcast:31
#undef DPP_STEP
    return v;
}

__global__ __launch_bounds__(BLOCK) void nll_rows_kernel(
    const float* __restrict__ pre,
    const int* __restrict__ y_true,
    float* __restrict__ partial) {
    const int lane = threadIdx.x & 63;
    const int wave = threadIdx.x >> 6;        // 0..3
    const int gwave = blockIdx.x * 4 + wave;  // global wave id

    float acc = 0.0f;

    int row = gwave;
    for (int it = 0; it < ITERS; ++it, row += NWAVES) {
        const v4f* rowp = reinterpret_cast<const v4f*>(pre + (size_t)row * C);
        v4f a = rowp[lane];        // cols [4*lane, 4*lane+4)
        v4f b = rowp[64 + lane];   // cols [256+4*lane, 256+4*lane+4)
        int t = y_true[row];       // wave-uniform broadcast load

        // ---- wave max (value only), 0 DS ----
        float m8 = fmaxf(fmaxf(fmaxf(a.x, a.y), fmaxf(a.z, a.w)),
                         fmaxf(fmaxf(b.x, b.y), fmaxf(b.z, b.w)));
        float vm = dpp_wave_max(m8);
        float M = __int_as_float(__builtin_amdgcn_readlane(__float_as_int(vm), 63));

        // ---- first-occurrence argmax via ballot (exact jnp.argmax semantics):
        // a-half cols (0..255) precede b-half (256..511); within a half, lane
        // order == column order; within a lane, descending writes keep the
        // earliest matching element. All scalar/VALU, 0 DS.
        int fA = 4;
        if (a.w == M) fA = 3;
        if (a.z == M) fA = 2;
        if (a.y == M) fA = 1;
        if (a.x == M) fA = 0;
        int fB = 4;
        if (b.w == M) fB = 3;
        if (b.z == M) fB = 2;
        if (b.y == M) fB = 1;
        if (b.x == M) fB = 0;
        unsigned long long mA = __ballot(fA < 4);
        unsigned long long mB = __ballot(fB < 4);

        int pred;
        if (mA) {
            int ol = __builtin_ctzll(mA);
            pred = ol * 4 + __builtin_amdgcn_readlane(fA, ol);
        } else {
            int ol = __builtin_ctzll(mB);
            pred = 256 + ol * 4 + __builtin_amdgcn_readlane(fB, ol);
        }

        // ---- register gather of pre[row][t] (t uniform): owner lane holds it.
        int tu = __builtin_amdgcn_readfirstlane(t);
        int e = tu & 3;
        int owner = (tu & 255) >> 2;
        bool hi = tu >= 256;
        float cx = hi ? b.x : a.x;
        float cy = hi ? b.y : a.y;
        float cz = hi ? b.z : a.z;
        float cw = hi ? b.w : a.w;
        float d0 = (e & 1) ? cy : cx;
        float d1 = (e & 1) ? cw : cz;
        float cand = (e & 2) ? d1 : d0;
        float g = __int_as_float(
            __builtin_amdgcn_readlane(__float_as_int(cand), owner));

        int d = pred - tu;
        float w = (d == 1 || d == -1) ? WEIGHT : 1.0f;
        acc += w * g;  // all quantities wave-uniform; every lane accumulates
    }

    __shared__ float ssum[4];
    if (lane == 0) ssum[wave] = acc;
    __syncthreads();
    if (threadIdx.x == 0) {
        partial[blockIdx.x] = ssum[0] + ssum[1] + ssum[2] + ssum[3];
    }
}

// Deterministic fixed-order reduction of the block partials.
__global__ __launch_bounds__(256) void nll_reduce_kernel(
    const float* __restrict__ partial, float* __restrict__ out, int n) {
    __shared__ float s[256];
    float acc = 0.0f;
    for (int i = threadIdx.x; i < n; i += 256) acc += partial[i];
    s[threadIdx.x] = acc;
    __syncthreads();
    for (int w = 128; w > 0; w >>= 1) {
        if (threadIdx.x < w) s[threadIdx.x] += s[threadIdx.x + w];
        __syncthreads();
    }
    if (threadIdx.x == 0) out[0] = s[0] * (1.0f / 64.0f);  // divide by B
}

extern "C" void kernel_launch(void* const* d_in, const int* in_sizes, int n_in,
                              void* d_out, int out_size, void* d_ws, size_t ws_size,
                              hipStream_t stream) {
    const float* pre = (const float*)d_in[0];
    const int* y_true = (const int*)d_in[1];
    float* out = (float*)d_out;
    float* partial = (float*)d_ws;  // NBLOCKS floats

    nll_rows_kernel<<<NBLOCKS, BLOCK, 0, stream>>>(pre, y_true, partial);
    nll_reduce_kernel<<<1, 256, 0, stream>>>(partial, out, NBLOCKS);
}

// Round 5
// 175.402 us; speedup vs baseline: 1.3175x; 1.1262x over previous
//
#include <hip/hip_runtime.h>

// Problem constants (from reference): B=64, S=8192, C=512
#define NROWS (64 * 8192)
#define C 512
#define WEIGHT 2.0f
#define NBLOCKS 2048
#define BLOCK 256                    // 4 waves per block
#define NWAVES (NBLOCKS * 4)         // 8192 waves
#define ITERS (NROWS / NWAVES)       // 64 rows per wave (exact)

// Native vector type so __builtin_nontemporal_load compiles.
typedef float v4f __attribute__((ext_vector_type(4)));

// R1 structure (best known: 189.9us) with ONE change: the two row loads are
// nontemporal. A 1GB read-once stream thrashes L2/Infinity-Cache; nt marks
// the lines no-retain. Within the R2/R3 unrolled structure nt was worth
// +26us (R3->R2); this tests it on the non-unrolled base.
__global__ __launch_bounds__(BLOCK) void nll_rows_kernel(
    const float* __restrict__ pre,
    const int* __restrict__ y_true,
    float* __restrict__ partial) {
    const int lane = threadIdx.x & 63;
    const int wave = threadIdx.x >> 6;        // 0..3
    const int gwave = blockIdx.x * 4 + wave;  // global wave id

    float acc = 0.0f;

    int row = gwave;
    for (int it = 0; it < ITERS; ++it, row += NWAVES) {
        const v4f* rowp = reinterpret_cast<const v4f*>(pre + (size_t)row * C);
        v4f a = __builtin_nontemporal_load(rowp + lane);       // cols [4l,4l+4)
        v4f b = __builtin_nontemporal_load(rowp + 64 + lane);  // cols [256+4l,..)

        // Lane-local argmax, ascending column order, strict > => first occurrence.
        int baseA = lane * 4;
        float mval = a.x; int midx = baseA;
        if (a.y > mval) { mval = a.y; midx = baseA + 1; }
        if (a.z > mval) { mval = a.z; midx = baseA + 2; }
        if (a.w > mval) { mval = a.w; midx = baseA + 3; }
        int baseB = 256 + lane * 4;
        if (b.x > mval) { mval = b.x; midx = baseB; }
        if (b.y > mval) { mval = b.y; midx = baseB + 1; }
        if (b.z > mval) { mval = b.z; midx = baseB + 2; }
        if (b.w > mval) { mval = b.w; midx = baseB + 3; }

        // Wave-wide argmax reduce; ties prefer smaller index (jnp.argmax).
        #pragma unroll
        for (int off = 1; off < 64; off <<= 1) {
            float oval = __shfl_xor(mval, off);
            int   oidx = __shfl_xor(midx, off);
            if (oval > mval || (oval == mval && oidx < midx)) {
                mval = oval; midx = oidx;
            }
        }

        int t = y_true[row];                         // wave-uniform (scalar path)
        float g = pre[(size_t)row * C + t];          // L1 hit (row just read)
        int d = midx - t;
        float w = (d == 1 || d == -1) ? WEIGHT : 1.0f;
        if (lane == 0) acc += w * g;
    }

    __shared__ float ssum[4];
    if (lane == 0) ssum[wave] = acc;
    __syncthreads();
    if (threadIdx.x == 0) {
        partial[blockIdx.x] = ssum[0] + ssum[1] + ssum[2] + ssum[3];
    }
}

// Deterministic fixed-order reduction of the block partials.
__global__ __launch_bounds__(256) void nll_reduce_kernel(
    const float* __restrict__ partial, float* __restrict__ out, int n) {
    __shared__ float s[256];
    float acc = 0.0f;
    for (int i = threadIdx.x; i < n; i += 256) acc += partial[i];
    s[threadIdx.x] = acc;
    __syncthreads();
    for (int w = 128; w > 0; w >>= 1) {
        if (threadIdx.x < w) s[threadIdx.x] += s[threadIdx.x + w];
        __syncthreads();
    }
    if (threadIdx.x == 0) out[0] = s[0] * (1.0f / 64.0f);  // divide by B
}

extern "C" void kernel_launch(void* const* d_in, const int* in_sizes, int n_in,
                              void* d_out, int out_size, void* d_ws, size_t ws_size,
                              hipStream_t stream) {
    const float* pre = (const float*)d_in[0];
    const int* y_true = (const int*)d_in[1];
    float* out = (float*)d_out;
    float* partial = (float*)d_ws;  // NBLOCKS floats

    nll_rows_kernel<<<NBLOCKS, BLOCK, 0, stream>>>(pre, y_true, partial);
    nll_reduce_kernel<<<1, 256, 0, stream>>>(partial, out, NBLOCKS);
}